// Round 3
// baseline (132.546 us; speedup 1.0000x reference)
//
#include <hip/hip_runtime.h>
#include <cstdint>
#include <cstddef>

// B=32, S=2048, P=256, N=256, K=8, L=4, M_out=1024
// out[b,t,n] = (A @ x_b)[t,n] + mean[b,n]*(1 - rowsumA[t]) + b_enc[t>>8]*std[b,n]
// where A[l*256+q, k*256+p] = W_enc[l,k] * (W^(8-k+l))[q,p].
// A is never materialized: GEMM stages bf16 W-powers (1.4 MB, L2-resident)
// and applies W_enc as an fp32 per-segment accumulator scale.

typedef unsigned short ushort_t;
typedef unsigned int uint_t;
typedef __attribute__((ext_vector_type(8))) short bf16x8;
typedef __attribute__((ext_vector_type(16))) float f32x16;

__device__ __forceinline__ ushort_t f32_to_bf16(float f) {
    uint_t u = __float_as_uint(f);
    u += 0x7FFFu + ((u >> 16) & 1u);   // RNE (finite values only here)
    return (ushort_t)(u >> 16);
}
__device__ __forceinline__ float bf16_to_f32(ushort_t h) {
    return __uint_as_float((uint_t)h << 16);
}

// ---------------- W powers: C = A * B for up to 4 (slot) triples ----------------
struct PowOps { int sa[4]; int sb[4]; int sd[4]; };

__global__ void powmul(float* __restrict__ Pw, PowOps ops) {
    __shared__ float As[2 * 256];
    const int mat = blockIdx.x;
    const int r0  = blockIdx.y * 2;      // 128 row-blocks of 2
    const int tid = threadIdx.x;         // 256
    const float* A  = Pw + (size_t)ops.sa[mat] * 65536;
    const float* Bm = Pw + (size_t)ops.sb[mat] * 65536;
    float* C        = Pw + (size_t)ops.sd[mat] * 65536;
    As[tid]       = A[(size_t)r0 * 256 + tid];
    As[tid + 256] = A[(size_t)r0 * 256 + 256 + tid];
    __syncthreads();
    float acc0 = 0.f, acc1 = 0.f;
    for (int p = 0; p < 256; p += 8) {
        float bv[8];
#pragma unroll
        for (int u = 0; u < 8; ++u) bv[u] = Bm[(size_t)(p + u) * 256 + tid];
        const float4 a00 = *(const float4*)(As + p);
        const float4 a01 = *(const float4*)(As + p + 4);
        const float4 a10 = *(const float4*)(As + 256 + p);
        const float4 a11 = *(const float4*)(As + 256 + p + 4);
        acc0 += a00.x*bv[0] + a00.y*bv[1] + a00.z*bv[2] + a00.w*bv[3]
              + a01.x*bv[4] + a01.y*bv[5] + a01.z*bv[6] + a01.w*bv[7];
        acc1 += a10.x*bv[0] + a10.y*bv[1] + a10.z*bv[2] + a10.w*bv[3]
              + a11.x*bv[4] + a11.y*bv[5] + a11.z*bv[6] + a11.w*bv[7];
    }
    C[(size_t)r0 * 256 + tid]       = acc0;
    C[(size_t)(r0 + 1) * 256 + tid] = acc1;
}

// ---------------- convert powers to bf16 ----------------
__global__ void convertPow(const float* __restrict__ Pw, ushort_t* __restrict__ Pb) {
    const int i = (blockIdx.x * 256 + threadIdx.x) * 4;   // 704 blocks covers 11*65536
    const float4 v = *(const float4*)(Pw + i);
    const uint_t lo = (uint_t)f32_to_bf16(v.x) | ((uint_t)f32_to_bf16(v.y) << 16);
    const uint_t hi = (uint_t)f32_to_bf16(v.z) | ((uint_t)f32_to_bf16(v.w) << 16);
    uint2 o; o.x = lo; o.y = hi;
    *(uint2*)(Pb + i) = o;
}

// ---------------- row sums of bf16 powers: prs[m][q] = sum_p bf16(W^m)[q,p] ----------------
__global__ void powRS(const ushort_t* __restrict__ Pb, float* __restrict__ prs) {
    const int m = blockIdx.x; const int q = threadIdx.x;
    const uint4* rp = (const uint4*)(Pb + (size_t)m * 65536 + q * 256);
    float s = 0.f;
    for (int i = 0; i < 32; ++i) {
        const uint4 v = rp[i];
        s += bf16_to_f32((ushort_t)(v.x & 0xffff)) + bf16_to_f32((ushort_t)(v.x >> 16))
           + bf16_to_f32((ushort_t)(v.y & 0xffff)) + bf16_to_f32((ushort_t)(v.y >> 16))
           + bf16_to_f32((ushort_t)(v.z & 0xffff)) + bf16_to_f32((ushort_t)(v.z >> 16))
           + bf16_to_f32((ushort_t)(v.w & 0xffff)) + bf16_to_f32((ushort_t)(v.w >> 16));
    }
    prs[m * 256 + q] = s;
}

// ---------------- rowsumA[t] = sum_k W_enc[l,k] * prs[l+7-k][q] ----------------
__global__ void rowsumAk(const float* __restrict__ prs, const float* __restrict__ Wenc,
                         float* __restrict__ rsA) {
    const int l = blockIdx.x; const int q = threadIdx.x;
    float s = 0.f;
#pragma unroll
    for (int k = 0; k < 8; ++k) s += Wenc[l * 8 + k] * prs[(l + 7 - k) * 256 + q];
    rsA[l * 256 + q] = s;
}

// ---------------- transpose + bf16 convert + stats partials (x read ONCE) ----------------
__global__ void transpose_stats(const float* __restrict__ x, ushort_t* __restrict__ Xt,
                                float* __restrict__ ps1, float* __restrict__ ps2) {
    __shared__ float lds[64 * 65];
    __shared__ float red1[16 * 64];
    __shared__ float red2[16 * 64];
    const int st = blockIdx.x;                     // s-tile 0..31
    const int nt = blockIdx.y;                     // n-tile 0..3
    const int b  = blockIdx.z;                     // 0..31
    const int tid = threadIdx.x;
    const int c = tid & 15, r = tid >> 4;
    const int s0 = st * 64;
    float s1[4] = {0,0,0,0}, s2[4] = {0,0,0,0};
#pragma unroll
    for (int it = 0; it < 4; ++it) {
        const int ii = r + it * 16;
        const float4 v = *(const float4*)(x + ((size_t)b * 2048 + s0 + ii) * 256 + nt * 64 + c * 4);
        const float vv[4] = {v.x, v.y, v.z, v.w};
#pragma unroll
        for (int j = 0; j < 4; ++j) {
            lds[ii * 65 + c * 4 + j] = vv[j];
            s1[j] += vv[j]; s2[j] += vv[j] * vv[j];
        }
    }
#pragma unroll
    for (int j = 0; j < 4; ++j) { red1[r * 64 + c * 4 + j] = s1[j]; red2[r * 64 + c * 4 + j] = s2[j]; }
    __syncthreads();
    if (tid < 64) {
        float a = 0.f, q = 0.f;
#pragma unroll
        for (int rr = 0; rr < 16; ++rr) { a += red1[rr * 64 + tid]; q += red2[rr * 64 + tid]; }
        const size_t o = (size_t)st * 8192 + b * 256 + nt * 64 + tid;
        ps1[o] = a; ps2[o] = q;
    }
#pragma unroll
    for (int step = 0; step < 8; ++step) {
        const int npr = step * 8 + (tid >> 5);     // n within tile
        const int sp  = (tid & 31) * 2;            // even s within tile
        const float f0 = lds[sp * 65 + npr];
        const float f1 = lds[(sp + 1) * 65 + npr];
        const uint_t packed = (uint_t)f32_to_bf16(f0) | ((uint_t)f32_to_bf16(f1) << 16);
        *(uint_t*)(Xt + ((size_t)b * 256 + nt * 64 + npr) * 2048 + s0 + sp) = packed;
    }
}

__global__ void stats_final(const float* __restrict__ ps1, const float* __restrict__ ps2,
                            float* __restrict__ meanv, float* __restrict__ stdv) {
    const int b = blockIdx.x; const int n = threadIdx.x;
    float s = 0.f, q = 0.f;
#pragma unroll
    for (int st = 0; st < 32; ++st) {
        s += ps1[(size_t)st * 8192 + b * 256 + n];
        q += ps2[(size_t)st * 8192 + b * 256 + n];
    }
    const float mean = s * (1.0f / 2048.0f);
    float var = q * (1.0f / 2048.0f) - mean * mean;
    var = fmaxf(var, 0.0f);
    meanv[b * 256 + n] = mean;
    stdv [b * 256 + n] = sqrtf(var + 1e-5f);
}

// ---------------- GEMM ----------------
// C[t, n'] = sum_k we[k] * (bf16(W^(l+8-k)) @ x_k)[q, n'],  t = l*256+q, n' = 0..8191
// BM=256 (one full l), BN=128, BK=64, 8 waves (4x2), dbuf LDS, counted vmcnt.
#define GLOAD_LDS16(gsrc, ldst) \
    __builtin_amdgcn_global_load_lds((const __attribute__((address_space(1))) void*)(gsrc), \
                                     (__attribute__((address_space(3))) void*)(ldst), 16, 0, 0)

__global__ __launch_bounds__(512, 1) void gemm_kernel(
    const ushort_t* __restrict__ Pb,     // 11 * 65536 bf16 powers
    const ushort_t* __restrict__ Xt,     // [8192][2048] bf16
    const float* __restrict__ Wenc,
    const float* __restrict__ meanv, const float* __restrict__ stdv,
    const float* __restrict__ rsA, const float* __restrict__ benc,
    float* __restrict__ out)
{
    __shared__ ushort_t sA[2][256 * 64];
    __shared__ ushort_t sX[2][128 * 64];

    // XCD swizzle: the 4 blocks sharing an X-slice (same bx) land on one XCD.
    const int flat = blockIdx.x + (blockIdx.y << 2);   // 0..255
    const int xcd = flat & 7;
    const int r   = flat >> 3;          // 0..31
    const int l   = r & 3;              // output l (rows l*256..+255)
    const int bx  = xcd + ((r >> 2) << 3);  // 0..63 (cols bx*128)

    const int tid  = threadIdx.x;
    const int lane = tid & 63;
    const int w    = tid >> 6;          // 0..7
    const int wm   = w >> 1;            // 0..3 (M quarter)
    const int wn   = w & 1;             // 0..1 (N half)
    const int li   = lane & 31, lg = lane >> 5;
    const int srow = lane >> 3, schunk = lane & 7;

    float we[8];
#pragma unroll
    for (int k = 0; k < 8; ++k) we[k] = Wenc[l * 8 + k];

#define STAGE(buf, kt) do { \
    const int slot_ = l + 7 - ((kt) >> 2); \
    const int p0_ = ((kt) & 3) * 64; \
    const ushort_t* abase_ = Pb + (size_t)slot_ * 65536 + p0_; \
    const ushort_t* xbase_ = Xt + (size_t)bx * 128 * 2048 + (kt) * 64; \
    _Pragma("unroll") \
    for (int i_ = 0; i_ < 4; ++i_) { \
        const int rr_ = i_ * 64 + w * 8 + srow; \
        const int ch_ = schunk ^ (rr_ & 7); \
        GLOAD_LDS16(abase_ + rr_ * 256 + ch_ * 8, &sA[buf][(i_ * 64 + w * 8) * 64]); \
    } \
    _Pragma("unroll") \
    for (int i_ = 0; i_ < 2; ++i_) { \
        const int rr_ = i_ * 64 + w * 8 + srow; \
        const int ch_ = schunk ^ (rr_ & 7); \
        GLOAD_LDS16(xbase_ + (size_t)rr_ * 2048 + ch_ * 8, &sX[buf][(i_ * 64 + w * 8) * 64]); \
    } \
} while (0)

    f32x16 acc[2][2], acc2[2][2];
#pragma unroll
    for (int mm = 0; mm < 2; ++mm)
#pragma unroll
        for (int nn = 0; nn < 2; ++nn)
#pragma unroll
            for (int rr = 0; rr < 16; ++rr) { acc[mm][nn][rr] = 0.0f; acc2[mm][nn][rr] = 0.0f; }

    STAGE(0, 0);
    for (int kt = 0; kt < 32; ++kt) {
        const int cur = kt & 1;
        if (kt < 31) {
            STAGE(cur ^ 1, kt + 1);
            asm volatile("s_waitcnt vmcnt(6)" ::: "memory");
        } else {
            asm volatile("s_waitcnt vmcnt(0)" ::: "memory");
        }
        __builtin_amdgcn_s_barrier();
        asm volatile("" ::: "memory");

        const ushort_t* sAc = &sA[cur][0];
        const ushort_t* sXc = &sX[cur][0];
#pragma unroll
        for (int ks = 0; ks < 4; ++ks) {
            bf16x8 af[2], xf[2];
#pragma unroll
            for (int mm = 0; mm < 2; ++mm) {
                const int row = wm * 64 + mm * 32 + li;
                const int ch  = (ks * 2 + lg) ^ (row & 7);
                af[mm] = *(const bf16x8*)(sAc + row * 64 + ch * 8);
            }
#pragma unroll
            for (int nn = 0; nn < 2; ++nn) {
                const int row = wn * 64 + nn * 32 + li;
                const int ch  = (ks * 2 + lg) ^ (row & 7);
                xf[nn] = *(const bf16x8*)(sXc + row * 64 + ch * 8);
            }
#pragma unroll
            for (int mm = 0; mm < 2; ++mm)
#pragma unroll
                for (int nn = 0; nn < 2; ++nn)
                    acc2[mm][nn] = __builtin_amdgcn_mfma_f32_32x32x16_bf16(af[mm], xf[nn], acc2[mm][nn], 0, 0, 0);
        }
        if ((kt & 3) == 3) {
            const float wk = we[kt >> 2];
#pragma unroll
            for (int mm = 0; mm < 2; ++mm)
#pragma unroll
                for (int nn = 0; nn < 2; ++nn)
#pragma unroll
                    for (int rr = 0; rr < 16; ++rr) {
                        acc[mm][nn][rr] += wk * acc2[mm][nn][rr];
                        acc2[mm][nn][rr] = 0.0f;
                    }
        }
        asm volatile("" ::: "memory");
        __builtin_amdgcn_s_barrier();
        asm volatile("" ::: "memory");
    }
#undef STAGE

    // epilogue: out = acc + mean*(1-rowsumA) + benc[l]*std
    const float be = benc[l];
    float sd[2], mn[2];
#pragma unroll
    for (int nn = 0; nn < 2; ++nn) {
        const int col = bx * 128 + wn * 64 + nn * 32 + li;   // 0..8191
        sd[nn] = stdv [col];
        mn[nn] = meanv[col];
    }
#pragma unroll
    for (int mm = 0; mm < 2; ++mm)
#pragma unroll
        for (int nn = 0; nn < 2; ++nn) {
            const int col = bx * 128 + wn * 64 + nn * 32 + li;
            const int bq = col >> 8, nq = col & 255;
            const float ben = be * sd[nn];
#pragma unroll
            for (int rr = 0; rr < 16; ++rr) {
                const int row = l * 256 + wm * 64 + mm * 32 + ((rr & 3) + 8 * (rr >> 2) + 4 * lg);
                const float rs = rsA[row];
                out[((size_t)bq * 1024 + row) * 256 + nq] =
                    acc[mm][nn][rr] + mn[nn] * (1.0f - rs) + ben;
            }
        }
}

// ---------------- launch ----------------
extern "C" void kernel_launch(void* const* d_in, const int* in_sizes, int n_in,
                              void* d_out, int out_size, void* d_ws, size_t ws_size,
                              hipStream_t stream) {
    (void)in_sizes; (void)n_in; (void)out_size; (void)ws_size;
    const float* x_enc  = (const float*)d_in[0];
    const float* W_base = (const float*)d_in[4];
    const float* W_enc  = (const float*)d_in[5];
    const float* b_enc  = (const float*)d_in[6];
    float* out = (float*)d_out;

    char* ws = (char*)d_ws;
    float*    wsP    = (float*)(ws);                 // 11*65536 f32 powers (2.75 MB)
    ushort_t* wsPb   = (ushort_t*)(ws + 0x300000);   // 11*65536 bf16 (1.38 MB)
    float*    wsPrs  = (float*)(ws + 0x480000);      // 11*256 f32
    float*    wsRsA  = (float*)(ws + 0x490000);      // 1024 f32
    float*    wsS1   = (float*)(ws + 0x4A0000);      // 32*8192 f32 (1 MB)
    float*    wsS2   = (float*)(ws + 0x5A0000);      // 1 MB
    float*    wsMean = (float*)(ws + 0x6A0000);      // 8192 f32
    float*    wsStd  = (float*)(ws + 0x6B0000);
    ushort_t* wsXt   = (ushort_t*)(ws + 0x700000);   // [8192][2048] bf16 (32 MB)

    hipMemcpyAsync(wsP, W_base, 256 * 256 * sizeof(float), hipMemcpyDeviceToDevice, stream);

    // powers: slot m-1 = W^m
    { PowOps o{{0, 0, 0, 0}, {0, 0, 0, 0}, {1, 0, 0, 0}};            // W2
      powmul<<<dim3(1, 128), 256, 0, stream>>>(wsP, o); }
    { PowOps o{{1, 1, 0, 0}, {0, 1, 0, 0}, {2, 3, 0, 0}};            // W3,W4
      powmul<<<dim3(2, 128), 256, 0, stream>>>(wsP, o); }
    { PowOps o{{3, 3, 3, 3}, {0, 1, 2, 3}, {4, 5, 6, 7}};            // W5..W8
      powmul<<<dim3(4, 128), 256, 0, stream>>>(wsP, o); }
    { PowOps o{{7, 7, 7, 0}, {0, 1, 2, 0}, {8, 9, 10, 0}};           // W9..W11
      powmul<<<dim3(3, 128), 256, 0, stream>>>(wsP, o); }

    convertPow<<<704, 256, 0, stream>>>(wsP, wsPb);
    powRS<<<11, 256, 0, stream>>>(wsPb, wsPrs);
    rowsumAk<<<4, 256, 0, stream>>>(wsPrs, W_enc, wsRsA);

    transpose_stats<<<dim3(32, 4, 32), 256, 0, stream>>>(x_enc, wsXt, wsS1, wsS2);
    stats_final<<<32, 256, 0, stream>>>(wsS1, wsS2, wsMean, wsStd);

    gemm_kernel<<<dim3(4, 64), 512, 0, stream>>>(wsPb, wsXt, W_enc, wsMean, wsStd,
                                                 wsRsA, b_enc, out);
}